// Round 2
// baseline (858.388 us; speedup 1.0000x reference)
//
#include <hip/hip_runtime.h>

// Problem constants (from reference setup_inputs)
#define NROWS 65536
#define DDIM 256
#define KCODES 1024

static __device__ __forceinline__ float4 ld4(const float* p) {
    return *reinterpret_cast<const float4*>(p);
}

// -------------------- row squared norms (fp64 accumulate) --------------------
__global__ void row_sqnorm_kernel(const float* __restrict__ X, float* __restrict__ out, int nrows) {
    int row = blockIdx.x * 4 + (threadIdx.x >> 6);
    if (row >= nrows) return;
    int lane = threadIdx.x & 63;
    float4 v = reinterpret_cast<const float4*>(X + (size_t)row * DDIM)[lane];
    double s = (double)v.x * v.x + (double)v.y * v.y + (double)v.z * v.z + (double)v.w * v.w;
    #pragma unroll
    for (int off = 32; off > 0; off >>= 1) s += __shfl_down(s, off);
    if (lane == 0) out[row] = (float)s;
}

// -------------------- argmin over K of ||x||^2 + ||c||^2 - 2 x.c --------------------
// Block: 256 threads. 64 rows/block, K chunked by 128, D tiled by 32.
// tx = tid&15 (k dimension), ty = tid>>4 (row dimension).
// Thread computes rows {i*16+ty : i<4} x ks {kc + j*16+tx : j<8}.
#define BR 64
#define KC 128
#define DC 32
#define PAD 36

__global__ __launch_bounds__(256) void argmin_kernel(
        const float* __restrict__ X, const float* __restrict__ C,
        const float* __restrict__ xsq, const float* __restrict__ csq,
        int* __restrict__ indices) {
    __shared__ float xt[BR][PAD];
    __shared__ float ct[KC][PAD];

    int tid = threadIdx.x;
    int tx = tid & 15;
    int ty = tid >> 4;
    int row0 = blockIdx.x * BR;

    float xs[4];
    #pragma unroll
    for (int i = 0; i < 4; i++) xs[i] = xsq[row0 + i * 16 + ty];

    float bestd[4];
    int bestk[4];
    #pragma unroll
    for (int i = 0; i < 4; i++) { bestd[i] = 3.0e38f; bestk[i] = 0; }

    for (int kc = 0; kc < KCODES; kc += KC) {
        float acc[4][8];
        #pragma unroll
        for (int i = 0; i < 4; i++)
            #pragma unroll
            for (int j = 0; j < 8; j++) acc[i][j] = 0.0f;

        for (int dt = 0; dt < DDIM; dt += DC) {
            __syncthreads();   // protect previous tile reads
            // stage x tile: 64x32 floats = 512 float4, 2 per thread
            #pragma unroll
            for (int it = 0; it < 2; it++) {
                int e = it * 256 + tid;
                int r = e >> 3, c4 = e & 7;
                float4 v = ld4(X + (size_t)(row0 + r) * DDIM + dt + c4 * 4);
                *reinterpret_cast<float4*>(&xt[r][c4 * 4]) = v;
            }
            // stage c tile: 128x32 floats = 1024 float4, 4 per thread
            #pragma unroll
            for (int it = 0; it < 4; it++) {
                int e = it * 256 + tid;
                int r = e >> 3, c4 = e & 7;
                float4 v = ld4(C + (size_t)(kc + r) * DDIM + dt + c4 * 4);
                *reinterpret_cast<float4*>(&ct[r][c4 * 4]) = v;
            }
            __syncthreads();

            for (int d4 = 0; d4 < DC; d4 += 4) {
                float4 xv[4], cv[8];
                #pragma unroll
                for (int i = 0; i < 4; i++)
                    xv[i] = *reinterpret_cast<const float4*>(&xt[i * 16 + ty][d4]);
                #pragma unroll
                for (int j = 0; j < 8; j++)
                    cv[j] = *reinterpret_cast<const float4*>(&ct[j * 16 + tx][d4]);
                #pragma unroll
                for (int i = 0; i < 4; i++) {
                    #pragma unroll
                    for (int j = 0; j < 8; j++) {
                        float a = acc[i][j];
                        a += xv[i].x * cv[j].x;
                        a += xv[i].y * cv[j].y;
                        a += xv[i].z * cv[j].z;
                        a += xv[i].w * cv[j].w;
                        acc[i][j] = a;
                    }
                }
            }
        }

        // epilogue: distances for this K chunk, running argmin
        float cs_r[8];
        #pragma unroll
        for (int j = 0; j < 8; j++) cs_r[j] = csq[kc + j * 16 + tx];

        #pragma unroll
        for (int i = 0; i < 4; i++) {
            float bd = 3.0e38f;
            int bk = 0;
            #pragma unroll
            for (int j = 0; j < 8; j++) {
                int kk = kc + j * 16 + tx;
                float t = xs[i] + cs_r[j];          // one fp32 rounding (matches ref)
                float dist = t - 2.0f * acc[i][j];  // 2*acc exact; one rounding
                if (dist < bd || (dist == bd && kk < bk)) { bd = dist; bk = kk; }
            }
            // reduce across the 16 tx lanes (lanes differing in bits 0..3)
            #pragma unroll
            for (int m = 1; m < 16; m <<= 1) {
                float od = __shfl_xor(bd, m);
                int ok = __shfl_xor(bk, m);
                if (od < bd || (od == bd && ok < bk)) { bd = od; bk = ok; }
            }
            if (bd < bestd[i] || (bd == bestd[i] && bk < bestk[i])) { bestd[i] = bd; bestk[i] = bk; }
        }
    }

    if (tx == 0) {
        #pragma unroll
        for (int i = 0; i < 4; i++) indices[row0 + i * 16 + ty] = bestk[i];
    }
}

// -------------------- scatter: counts + dw segment sums --------------------
__global__ void scatter_kernel(const float* __restrict__ Z, const int* __restrict__ idx,
                               int* __restrict__ counts, float* __restrict__ dw) {
    int row = blockIdx.x * 4 + (threadIdx.x >> 6);
    int lane = threadIdx.x & 63;
    int k = idx[row];
    float4 v = reinterpret_cast<const float4*>(Z + (size_t)row * DDIM)[lane];
    float* dst = dw + (size_t)k * DDIM + lane * 4;
    atomicAdd(dst + 0, v.x);
    atomicAdd(dst + 1, v.y);
    atomicAdd(dst + 2, v.z);
    atomicAdd(dst + 3, v.w);
    if (lane == 0) atomicAdd(&counts[k], 1);
}

// -------------------- EMA update --------------------
__global__ void ema_kernel(const float* __restrict__ ema_count, const float* __restrict__ ema_w,
                           const int* __restrict__ counts, const float* __restrict__ dw,
                           float* __restrict__ emb_new, float* __restrict__ cnt_new,
                           float* __restrict__ w_new) {
    const float DEC = (float)0.99;          // fp32(0.99)
    const float OMD = (float)(1.0 - 0.99);  // fp32(0.010000000000000009)
    int i = blockIdx.x * 256 + threadIdx.x;    // float4 index over K*D/4
    int k = i >> 6;                            // D/4 = 64 float4 per code
    float cf = (float)counts[k];
    float cn = __fadd_rn(__fmul_rn(DEC, ema_count[k]), __fmul_rn(OMD, cf));
    float4 w = reinterpret_cast<const float4*>(ema_w)[i];
    float4 d = reinterpret_cast<const float4*>(dw)[i];
    float4 wn, en;
    wn.x = __fadd_rn(__fmul_rn(DEC, w.x), __fmul_rn(OMD, d.x));
    wn.y = __fadd_rn(__fmul_rn(DEC, w.y), __fmul_rn(OMD, d.y));
    wn.z = __fadd_rn(__fmul_rn(DEC, w.z), __fmul_rn(OMD, d.z));
    wn.w = __fadd_rn(__fmul_rn(DEC, w.w), __fmul_rn(OMD, d.w));
    en.x = __fdiv_rn(wn.x, cn);
    en.y = __fdiv_rn(wn.y, cn);
    en.z = __fdiv_rn(wn.z, cn);
    en.w = __fdiv_rn(wn.w, cn);
    reinterpret_cast<float4*>(w_new)[i] = wn;
    reinterpret_cast<float4*>(emb_new)[i] = en;
    if ((i & 63) == 0) cnt_new[k] = cn;
}

// -------------------- gathers --------------------
__global__ void gather_kernel(const float* __restrict__ emb, const float* __restrict__ emb_new,
                              const int* __restrict__ idx, float* __restrict__ zq,
                              float* __restrict__ zqb) {
    int row = blockIdx.x * 4 + (threadIdx.x >> 6);
    int lane = threadIdx.x & 63;
    int k = idx[row];
    float4 a = reinterpret_cast<const float4*>(emb + (size_t)k * DDIM)[lane];
    float4 b = reinterpret_cast<const float4*>(emb_new + (size_t)k * DDIM)[lane];
    reinterpret_cast<float4*>(zq + (size_t)row * DDIM)[lane] = a;
    reinterpret_cast<float4*>(zqb + (size_t)row * DDIM)[lane] = b;
}

extern "C" void kernel_launch(void* const* d_in, const int* in_sizes, int n_in,
                              void* d_out, int out_size, void* d_ws, size_t ws_size,
                              hipStream_t stream) {
    const float* x = (const float*)d_in[0];         // masked_z_e_x [N,D]
    const float* z = (const float*)d_in[1];         // z_e_x        [N,D]
    const float* emb = (const float*)d_in[2];       // embedding    [K,D]
    const float* ema_count = (const float*)d_in[3]; // [K]
    const float* ema_w = (const float*)d_in[4];     // [K,D]

    const int N = in_sizes[0] / DDIM;   // 65536
    const int K = in_sizes[3];          // 1024

    float* out = (float*)d_out;
    float* zq = out;                                  // N*D
    float* zqb = zq + (size_t)N * DDIM;               // N*D
    float* emb_new = zqb + (size_t)N * DDIM;          // K*D
    float* cnt_new = emb_new + (size_t)K * DDIM;      // K
    float* w_new = cnt_new + K;                       // K*D

    // workspace layout
    float* xsq = (float*)d_ws;                        // N floats
    float* csq = xsq + N;                             // K floats
    int* indices = (int*)(csq + K);                   // N ints
    int* counts = indices + N;                        // K ints
    float* dw = (float*)(counts + K);                 // K*D floats

    // zero counts + dw (contiguous)
    hipMemsetAsync(counts, 0, (size_t)(K + (size_t)K * DDIM) * sizeof(float), stream);

    row_sqnorm_kernel<<<N / 4, 256, 0, stream>>>(x, xsq, N);
    row_sqnorm_kernel<<<K / 4, 256, 0, stream>>>(emb, csq, K);
    argmin_kernel<<<N / BR, 256, 0, stream>>>(x, emb, xsq, csq, indices);
    scatter_kernel<<<N / 4, 256, 0, stream>>>(z, indices, counts, dw);
    ema_kernel<<<(K * DDIM / 4) / 256, 256, 0, stream>>>(ema_count, ema_w, counts, dw,
                                                         emb_new, cnt_new, w_new);
    gather_kernel<<<N / 4, 256, 0, stream>>>(emb, emb_new, indices, zq, zqb);
}

// Round 3
// 740.899 us; speedup vs baseline: 1.1586x; 1.1586x over previous
//
#include <hip/hip_runtime.h>

#define DDIM 256
#define KCODES 1024
#define MARGIN 2.0e-4f

typedef __attribute__((ext_vector_type(8))) short fragA;
typedef __attribute__((ext_vector_type(4))) float f32x4;

static __device__ __forceinline__ float4 ld4(const float* p) {
    return *reinterpret_cast<const float4*>(p);
}

static __device__ __forceinline__ ushort bf16_rne(float f) {
    unsigned bits = __float_as_uint(f);
    unsigned r = bits + 0x7FFFu + ((bits >> 16) & 1u);
    return (ushort)(r >> 16);
}

// ============ fused split (hi/lo bf16 planes) + row squared norm ============
__global__ void split_sqnorm_kernel(const float* __restrict__ X, ushort* __restrict__ Xs,
                                    float* __restrict__ out, int nrows) {
    int row = blockIdx.x * 4 + (threadIdx.x >> 6);
    if (row >= nrows) return;
    int lane = threadIdx.x & 63;
    float4 v = reinterpret_cast<const float4*>(X + (size_t)row * DDIM)[lane];
    double s = (double)v.x * v.x + (double)v.y * v.y + (double)v.z * v.z + (double)v.w * v.w;
    #pragma unroll
    for (int off = 32; off > 0; off >>= 1) s += __shfl_down(s, off);
    if (lane == 0) out[row] = (float)s;

    float fv[4] = {v.x, v.y, v.z, v.w};
    ushort hb[4], lb[4];
    #pragma unroll
    for (int i = 0; i < 4; i++) {
        hb[i] = bf16_rne(fv[i]);
        float hf = __uint_as_float((unsigned)hb[i] << 16);
        lb[i] = bf16_rne(fv[i] - hf);
    }
    ushort4 hi = make_ushort4(hb[0], hb[1], hb[2], hb[3]);
    ushort4 lo = make_ushort4(lb[0], lb[1], lb[2], lb[3]);
    *reinterpret_cast<ushort4*>(Xs + (size_t)row * 512 + lane * 4) = hi;
    *reinterpret_cast<ushort4*>(Xs + (size_t)row * 512 + 256 + lane * 4) = lo;
}

// ============ MFMA argmin: dists[n,k] via 3-pass split-bf16, top-2 tracking ============
// Block 256 thr = 4 waves; block covers 64 rows; loop k-chunks of 64.
// Wave w: rows w*16..w*16+15. A-frags (X) held in registers for all 8 d-steps.
// C chunk staged in LDS (64 rows x 512 ushort, XOR-swizzled 16B chunks).
__global__ __launch_bounds__(256) void argmin_mfma_kernel(
        const ushort* __restrict__ Xs, const ushort* __restrict__ Cs,
        const float* __restrict__ xsq, const float* __restrict__ csq,
        int* __restrict__ indices, int* __restrict__ flag_cnt,
        int* __restrict__ flag_list, int nrows_total) {
    __shared__ ushort clds[64 * 512];   // 64 KB

    int tid = threadIdx.x;
    int w = tid >> 6;
    int l = tid & 63;
    int lm = l & 15;       // A row within tile / D col (k)
    int lg = l >> 4;       // d-group / D row-group
    int row0 = blockIdx.x * 64;

    // A fragments: row = row0 + w*16 + lm, 8 d-steps, hi+lo planes
    const ushort* xrow = Xs + (size_t)(row0 + w * 16 + lm) * 512;
    fragA a_hi[8], a_lo[8];
    #pragma unroll
    for (int s = 0; s < 8; s++) {
        a_hi[s] = *reinterpret_cast<const fragA*>(xrow + s * 32 + lg * 8);
        a_lo[s] = *reinterpret_cast<const fragA*>(xrow + 256 + s * 32 + lg * 8);
    }

    // output rows this lane owns: row0 + w*16 + lg*4 + r
    float xs_r[4];
    #pragma unroll
    for (int r = 0; r < 4; r++) xs_r[r] = xsq[row0 + w * 16 + lg * 4 + r];

    float d1[4], d2[4];
    int k1[4];
    #pragma unroll
    for (int r = 0; r < 4; r++) { d1[r] = 3.0e38f; d2[r] = 3.0e38f; k1[r] = 0; }

    for (int kc = 0; kc < KCODES; kc += 64) {
        __syncthreads();   // protect previous chunk reads
        // stage C chunk: 64 rows x 64 16B-chunks, swizzled: pos = chunk ^ (row&7)
        #pragma unroll
        for (int it = 0; it < 16; it++) {
            int c = it * 256 + tid;
            int r = c >> 6, col = c & 63;
            int p = (col & 32) | ((col & 31) ^ (r & 7));
            *reinterpret_cast<float4*>(&clds[r * 512 + p * 8]) =
                *reinterpret_cast<const float4*>(Cs + (size_t)(kc + r) * 512 + col * 8);
        }
        __syncthreads();

        f32x4 acc[4];
        #pragma unroll
        for (int kt = 0; kt < 4; kt++) acc[kt] = (f32x4){0.f, 0.f, 0.f, 0.f};

        #pragma unroll
        for (int s = 0; s < 8; s++) {
            #pragma unroll
            for (int kt = 0; kt < 4; kt++) {
                int kl = kt * 16 + lm;
                int chi = (4 * s + lg) ^ (kl & 7);
                fragA bhi = *reinterpret_cast<const fragA*>(&clds[kl * 512 + chi * 8]);
                fragA blo = *reinterpret_cast<const fragA*>(&clds[kl * 512 + (32 + chi) * 8]);
                acc[kt] = __builtin_amdgcn_mfma_f32_16x16x32_bf16(a_hi[s], bhi, acc[kt], 0, 0, 0);
                acc[kt] = __builtin_amdgcn_mfma_f32_16x16x32_bf16(a_lo[s], bhi, acc[kt], 0, 0, 0);
                acc[kt] = __builtin_amdgcn_mfma_f32_16x16x32_bf16(a_hi[s], blo, acc[kt], 0, 0, 0);
            }
        }

        // epilogue: lane holds D[lg*4+r][lm] for 4 k-tiles; k = kc + kt*16 + lm
        #pragma unroll
        for (int kt = 0; kt < 4; kt++) {
            int k = kc + kt * 16 + lm;
            float cs = csq[k];
            #pragma unroll
            for (int r = 0; r < 4; r++) {
                float dist = (xs_r[r] + cs) - 2.0f * acc[kt][r];
                if (dist < d1[r] || (dist == d1[r] && k < k1[r])) {
                    d2[r] = d1[r]; d1[r] = dist; k1[r] = k;
                } else if (dist < d2[r]) {
                    d2[r] = dist;
                }
            }
        }
    }

    // reduce top-2 across the 16 lanes sharing (lg): xor masks 1,2,4,8
    #pragma unroll
    for (int r = 0; r < 4; r++) {
        float bd1 = d1[r], bd2 = d2[r];
        int bk1 = k1[r];
        #pragma unroll
        for (int m = 1; m < 16; m <<= 1) {
            float od1 = __shfl_xor(bd1, m);
            int ok1 = __shfl_xor(bk1, m);
            float od2 = __shfl_xor(bd2, m);
            if (od1 < bd1 || (od1 == bd1 && ok1 < bk1)) {
                bd2 = fminf(bd1, od2); bd1 = od1; bk1 = ok1;
            } else {
                bd2 = fminf(bd2, od1);
            }
        }
        if (lm == 0) {
            int row = row0 + w * 16 + lg * 4 + r;
            indices[row] = bk1;
            if (bd2 - bd1 < MARGIN) {
                int pos = atomicAdd(flag_cnt, 1);
                if (pos < nrows_total) flag_list[pos] = row;
            }
        }
    }
}

// ============ exact fp32 recompute for flagged (near-tie) rows ============
__global__ __launch_bounds__(256) void exact_recheck_kernel(
        const float* __restrict__ X, const float* __restrict__ C,
        const float* __restrict__ xsq, const float* __restrict__ csq,
        const int* __restrict__ flag_cnt, const int* __restrict__ flag_list,
        int* __restrict__ indices, int nrows_total) {
    __shared__ float xlds[16][256];
    __shared__ float xsh[16];
    __shared__ unsigned long long best[16];
    int cnt = *flag_cnt;
    if (cnt > nrows_total) cnt = nrows_total;
    int tid = threadIdx.x;

    for (int base = blockIdx.x * 16; base < cnt; base += gridDim.x * 16) {
        int nr = min(16, cnt - base);
        __syncthreads();
        for (int e = tid; e < nr * 64; e += 256) {
            int r = e >> 6, c4 = e & 63;
            int row = flag_list[base + r];
            reinterpret_cast<float4*>(xlds[r])[c4] =
                reinterpret_cast<const float4*>(X + (size_t)row * DDIM)[c4];
        }
        if (tid < nr) xsh[tid] = xsq[flag_list[base + tid]];
        if (tid < 16) best[tid] = 0xFFFFFFFFFFFFFFFFULL;
        __syncthreads();

        for (int j = 0; j < 4; j++) {
            int k = tid + 256 * j;
            const float* crow = C + (size_t)k * DDIM;
            float acc[16];
            #pragma unroll
            for (int r = 0; r < 16; r++) acc[r] = 0.f;
            for (int d4 = 0; d4 < 64; d4++) {
                float4 cv = reinterpret_cast<const float4*>(crow)[d4];
                #pragma unroll
                for (int r = 0; r < 16; r++) {
                    float4 xv = reinterpret_cast<const float4*>(xlds[r])[d4];
                    acc[r] += xv.x * cv.x; acc[r] += xv.y * cv.y;
                    acc[r] += xv.z * cv.z; acc[r] += xv.w * cv.w;
                }
            }
            float cs = csq[k];
            #pragma unroll
            for (int r = 0; r < 16; r++) {
                float t = xsh[r] + cs;
                float dist = t - 2.0f * acc[r];
                unsigned long long pk =
                    ((unsigned long long)__float_as_uint(dist) << 32) | (unsigned)k;
                atomicMin(&best[r], pk);
            }
        }
        __syncthreads();
        if (tid < nr) indices[flag_list[base + tid]] = (int)(best[tid] & 0xFFFFFFFFULL);
    }
}

// ============ round-2 fallback: fp32 argmin + sqnorm (used if ws too small) ============
__global__ void row_sqnorm_kernel(const float* __restrict__ X, float* __restrict__ out, int nrows) {
    int row = blockIdx.x * 4 + (threadIdx.x >> 6);
    if (row >= nrows) return;
    int lane = threadIdx.x & 63;
    float4 v = reinterpret_cast<const float4*>(X + (size_t)row * DDIM)[lane];
    double s = (double)v.x * v.x + (double)v.y * v.y + (double)v.z * v.z + (double)v.w * v.w;
    #pragma unroll
    for (int off = 32; off > 0; off >>= 1) s += __shfl_down(s, off);
    if (lane == 0) out[row] = (float)s;
}

#define BR 64
#define KC 128
#define DC 32
#define PAD 36

__global__ __launch_bounds__(256) void argmin_kernel(
        const float* __restrict__ X, const float* __restrict__ C,
        const float* __restrict__ xsq, const float* __restrict__ csq,
        int* __restrict__ indices) {
    __shared__ float xt[BR][PAD];
    __shared__ float ct[KC][PAD];
    int tid = threadIdx.x;
    int tx = tid & 15;
    int ty = tid >> 4;
    int row0 = blockIdx.x * BR;
    float xs[4];
    #pragma unroll
    for (int i = 0; i < 4; i++) xs[i] = xsq[row0 + i * 16 + ty];
    float bestd[4]; int bestk[4];
    #pragma unroll
    for (int i = 0; i < 4; i++) { bestd[i] = 3.0e38f; bestk[i] = 0; }
    for (int kc = 0; kc < KCODES; kc += KC) {
        float acc[4][8];
        #pragma unroll
        for (int i = 0; i < 4; i++)
            #pragma unroll
            for (int j = 0; j < 8; j++) acc[i][j] = 0.0f;
        for (int dt = 0; dt < DDIM; dt += DC) {
            __syncthreads();
            #pragma unroll
            for (int it = 0; it < 2; it++) {
                int e = it * 256 + tid;
                int r = e >> 3, c4 = e & 7;
                *reinterpret_cast<float4*>(&xt[r][c4 * 4]) = ld4(X + (size_t)(row0 + r) * DDIM + dt + c4 * 4);
            }
            #pragma unroll
            for (int it = 0; it < 4; it++) {
                int e = it * 256 + tid;
                int r = e >> 3, c4 = e & 7;
                *reinterpret_cast<float4*>(&ct[r][c4 * 4]) = ld4(C + (size_t)(kc + r) * DDIM + dt + c4 * 4);
            }
            __syncthreads();
            for (int d4 = 0; d4 < DC; d4 += 4) {
                float4 xv[4], cv[8];
                #pragma unroll
                for (int i = 0; i < 4; i++) xv[i] = *reinterpret_cast<const float4*>(&xt[i * 16 + ty][d4]);
                #pragma unroll
                for (int j = 0; j < 8; j++) cv[j] = *reinterpret_cast<const float4*>(&ct[j * 16 + tx][d4]);
                #pragma unroll
                for (int i = 0; i < 4; i++)
                    #pragma unroll
                    for (int j = 0; j < 8; j++) {
                        float a = acc[i][j];
                        a += xv[i].x * cv[j].x; a += xv[i].y * cv[j].y;
                        a += xv[i].z * cv[j].z; a += xv[i].w * cv[j].w;
                        acc[i][j] = a;
                    }
            }
        }
        float cs_r[8];
        #pragma unroll
        for (int j = 0; j < 8; j++) cs_r[j] = csq[kc + j * 16 + tx];
        #pragma unroll
        for (int i = 0; i < 4; i++) {
            float bd = 3.0e38f; int bk = 0;
            #pragma unroll
            for (int j = 0; j < 8; j++) {
                int kk = kc + j * 16 + tx;
                float t = xs[i] + cs_r[j];
                float dist = t - 2.0f * acc[i][j];
                if (dist < bd || (dist == bd && kk < bk)) { bd = dist; bk = kk; }
            }
            #pragma unroll
            for (int m = 1; m < 16; m <<= 1) {
                float od = __shfl_xor(bd, m);
                int ok = __shfl_xor(bk, m);
                if (od < bd || (od == bd && ok < bk)) { bd = od; bk = ok; }
            }
            if (bd < bestd[i] || (bd == bestd[i] && bk < bestk[i])) { bestd[i] = bd; bestk[i] = bk; }
        }
    }
    if (tx == 0) {
        #pragma unroll
        for (int i = 0; i < 4; i++) indices[row0 + i * 16 + ty] = bestk[i];
    }
}

// ============ scatter / ema / gather (unchanged from validated round 2) ============
__global__ void scatter_kernel(const float* __restrict__ Z, const int* __restrict__ idx,
                               int* __restrict__ counts, float* __restrict__ dw) {
    int row = blockIdx.x * 4 + (threadIdx.x >> 6);
    int lane = threadIdx.x & 63;
    int k = idx[row];
    float4 v = reinterpret_cast<const float4*>(Z + (size_t)row * DDIM)[lane];
    float* dst = dw + (size_t)k * DDIM + lane * 4;
    atomicAdd(dst + 0, v.x);
    atomicAdd(dst + 1, v.y);
    atomicAdd(dst + 2, v.z);
    atomicAdd(dst + 3, v.w);
    if (lane == 0) atomicAdd(&counts[k], 1);
}

__global__ void ema_kernel(const float* __restrict__ ema_count, const float* __restrict__ ema_w,
                           const int* __restrict__ counts, const float* __restrict__ dw,
                           float* __restrict__ emb_new, float* __restrict__ cnt_new,
                           float* __restrict__ w_new) {
    const float DEC = 0.99f;
    const float OMD = (float)(1.0 - 0.99);
    int i = blockIdx.x * 256 + threadIdx.x;
    int k = i >> 6;
    float cf = (float)counts[k];
    float cn = __fadd_rn(__fmul_rn(DEC, ema_count[k]), __fmul_rn(OMD, cf));
    float4 w = reinterpret_cast<const float4*>(ema_w)[i];
    float4 d = reinterpret_cast<const float4*>(dw)[i];
    float4 wn, en;
    wn.x = __fadd_rn(__fmul_rn(DEC, w.x), __fmul_rn(OMD, d.x));
    wn.y = __fadd_rn(__fmul_rn(DEC, w.y), __fmul_rn(OMD, d.y));
    wn.z = __fadd_rn(__fmul_rn(DEC, w.z), __fmul_rn(OMD, d.z));
    wn.w = __fadd_rn(__fmul_rn(DEC, w.w), __fmul_rn(OMD, d.w));
    en.x = __fdiv_rn(wn.x, cn);
    en.y = __fdiv_rn(wn.y, cn);
    en.z = __fdiv_rn(wn.z, cn);
    en.w = __fdiv_rn(wn.w, cn);
    reinterpret_cast<float4*>(w_new)[i] = wn;
    reinterpret_cast<float4*>(emb_new)[i] = en;
    if ((i & 63) == 0) cnt_new[k] = cn;
}

__global__ void gather_kernel(const float* __restrict__ emb, const float* __restrict__ emb_new,
                              const int* __restrict__ idx, float* __restrict__ zq,
                              float* __restrict__ zqb) {
    int row = blockIdx.x * 4 + (threadIdx.x >> 6);
    int lane = threadIdx.x & 63;
    int k = idx[row];
    float4 a = reinterpret_cast<const float4*>(emb + (size_t)k * DDIM)[lane];
    float4 b = reinterpret_cast<const float4*>(emb_new + (size_t)k * DDIM)[lane];
    reinterpret_cast<float4*>(zq + (size_t)row * DDIM)[lane] = a;
    reinterpret_cast<float4*>(zqb + (size_t)row * DDIM)[lane] = b;
}

extern "C" void kernel_launch(void* const* d_in, const int* in_sizes, int n_in,
                              void* d_out, int out_size, void* d_ws, size_t ws_size,
                              hipStream_t stream) {
    const float* x = (const float*)d_in[0];
    const float* z = (const float*)d_in[1];
    const float* emb = (const float*)d_in[2];
    const float* ema_count = (const float*)d_in[3];
    const float* ema_w = (const float*)d_in[4];

    const int N = in_sizes[0] / DDIM;   // 65536
    const int K = in_sizes[3];          // 1024

    float* out = (float*)d_out;
    float* zq = out;
    float* zqb = zq + (size_t)N * DDIM;
    float* emb_new = zqb + (size_t)N * DDIM;
    float* cnt_new = emb_new + (size_t)K * DDIM;
    float* w_new = cnt_new + K;

    // new-path workspace layout (bytes)
    char* wsb = (char*)d_ws;
    size_t off = 0;
    ushort* xsplit = (ushort*)(wsb + off); off += (size_t)N * 512 * 2;      // 64 MiB
    ushort* csplit = (ushort*)(wsb + off); off += (size_t)K * 512 * 2;      // 1 MiB
    float* xsq = (float*)(wsb + off); off += (size_t)N * 4;
    float* csq = (float*)(wsb + off); off += (size_t)K * 4;
    int* indices = (int*)(wsb + off); off += (size_t)N * 4;
    int* flag_list = (int*)(wsb + off); off += (size_t)N * 4;
    int* counts = (int*)(wsb + off); off += (size_t)K * 4;
    int* flag_cnt = (int*)(wsb + off); off += 16;
    float* dw = (float*)(wsb + off); off += (size_t)K * DDIM * 4;
    size_t need = off;

    if (ws_size >= need) {
        // zero counts + flag_cnt + dw (contiguous)
        hipMemsetAsync(counts, 0, (size_t)K * 4 + 16 + (size_t)K * DDIM * 4, stream);
        split_sqnorm_kernel<<<N / 4, 256, 0, stream>>>(x, xsplit, xsq, N);
        split_sqnorm_kernel<<<K / 4, 256, 0, stream>>>(emb, csplit, csq, K);
        argmin_mfma_kernel<<<N / 64, 256, 0, stream>>>(xsplit, csplit, xsq, csq,
                                                       indices, flag_cnt, flag_list, N);
        exact_recheck_kernel<<<128, 256, 0, stream>>>(x, emb, xsq, csq,
                                                      flag_cnt, flag_list, indices, N);
    } else {
        // fallback: round-2 validated fp32 path (ws layout: xsq, csq, indices, counts, dw)
        float* f_xsq = (float*)d_ws;
        float* f_csq = f_xsq + N;
        int* f_indices = (int*)(f_csq + K);
        int* f_counts = f_indices + N;
        float* f_dw = (float*)(f_counts + K);
        hipMemsetAsync(f_counts, 0, (size_t)(K + (size_t)K * DDIM) * sizeof(float), stream);
        row_sqnorm_kernel<<<N / 4, 256, 0, stream>>>(x, f_xsq, N);
        row_sqnorm_kernel<<<K / 4, 256, 0, stream>>>(emb, f_csq, K);
        argmin_kernel<<<N / BR, 256, 0, stream>>>(x, emb, f_xsq, f_csq, f_indices);
        // alias the rest of the launch sequence onto the fallback pointers
        scatter_kernel<<<N / 4, 256, 0, stream>>>(z, f_indices, f_counts, f_dw);
        ema_kernel<<<(K * DDIM / 4) / 256, 256, 0, stream>>>(ema_count, ema_w, f_counts, f_dw,
                                                             emb_new, cnt_new, w_new);
        gather_kernel<<<N / 4, 256, 0, stream>>>(emb, emb_new, f_indices, zq, zqb);
        return;
    }

    scatter_kernel<<<N / 4, 256, 0, stream>>>(z, indices, counts, dw);
    ema_kernel<<<(K * DDIM / 4) / 256, 256, 0, stream>>>(ema_count, ema_w, counts, dw,
                                                         emb_new, cnt_new, w_new);
    gather_kernel<<<N / 4, 256, 0, stream>>>(emb, emb_new, indices, zq, zqb);
}

// Round 5
// 547.717 us; speedup vs baseline: 1.5672x; 1.3527x over previous
//
#include <hip/hip_runtime.h>

#define DDIM 256
#define KCODES 1024
#define MARGIN 2.0e-4f

typedef __attribute__((ext_vector_type(8))) short fragA;
typedef __attribute__((ext_vector_type(4))) float f32x4;

static __device__ __forceinline__ float4 ld4(const float* p) {
    return *reinterpret_cast<const float4*>(p);
}

static __device__ __forceinline__ ushort bf16_rne(float f) {
    unsigned bits = __float_as_uint(f);
    unsigned r = bits + 0x7FFFu + ((bits >> 16) & 1u);
    return (ushort)(r >> 16);
}

// ============ fused split (hi/lo bf16 planes) + row squared norm ============
__global__ void split_sqnorm_kernel(const float* __restrict__ X, ushort* __restrict__ Xs,
                                    float* __restrict__ out, int nrows) {
    int row = blockIdx.x * 4 + (threadIdx.x >> 6);
    if (row >= nrows) return;
    int lane = threadIdx.x & 63;
    float4 v = reinterpret_cast<const float4*>(X + (size_t)row * DDIM)[lane];
    double s = (double)v.x * v.x + (double)v.y * v.y + (double)v.z * v.z + (double)v.w * v.w;
    #pragma unroll
    for (int off = 32; off > 0; off >>= 1) s += __shfl_down(s, off);
    if (lane == 0) out[row] = (float)s;

    float fv[4] = {v.x, v.y, v.z, v.w};
    ushort hb[4], lb[4];
    #pragma unroll
    for (int i = 0; i < 4; i++) {
        hb[i] = bf16_rne(fv[i]);
        float hf = __uint_as_float((unsigned)hb[i] << 16);
        lb[i] = bf16_rne(fv[i] - hf);
    }
    ushort4 hi = make_ushort4(hb[0], hb[1], hb[2], hb[3]);
    ushort4 lo = make_ushort4(lb[0], lb[1], lb[2], lb[3]);
    *reinterpret_cast<ushort4*>(Xs + (size_t)row * 512 + lane * 4) = hi;
    *reinterpret_cast<ushort4*>(Xs + (size_t)row * 512 + 256 + lane * 4) = lo;
}

// ============ MFMA argmin: dists[n,k] via 3-pass split-bf16, top-2 tracking ============
__global__ __launch_bounds__(256) void argmin_mfma_kernel(
        const ushort* __restrict__ Xs, const ushort* __restrict__ Cs,
        const float* __restrict__ xsq, const float* __restrict__ csq,
        int* __restrict__ indices, int* __restrict__ flag_cnt,
        int* __restrict__ flag_list, int nrows_total) {
    __shared__ ushort clds[64 * 512];   // 64 KB

    int tid = threadIdx.x;
    int w = tid >> 6;
    int l = tid & 63;
    int lm = l & 15;
    int lg = l >> 4;
    int row0 = blockIdx.x * 64;

    const ushort* xrow = Xs + (size_t)(row0 + w * 16 + lm) * 512;
    fragA a_hi[8], a_lo[8];
    #pragma unroll
    for (int s = 0; s < 8; s++) {
        a_hi[s] = *reinterpret_cast<const fragA*>(xrow + s * 32 + lg * 8);
        a_lo[s] = *reinterpret_cast<const fragA*>(xrow + 256 + s * 32 + lg * 8);
    }

    float xs_r[4];
    #pragma unroll
    for (int r = 0; r < 4; r++) xs_r[r] = xsq[row0 + w * 16 + lg * 4 + r];

    float d1[4], d2[4];
    int k1[4];
    #pragma unroll
    for (int r = 0; r < 4; r++) { d1[r] = 3.0e38f; d2[r] = 3.0e38f; k1[r] = 0; }

    for (int kc = 0; kc < KCODES; kc += 64) {
        __syncthreads();
        #pragma unroll
        for (int it = 0; it < 16; it++) {
            int c = it * 256 + tid;
            int r = c >> 6, col = c & 63;
            int p = (col & 32) | ((col & 31) ^ (r & 7));
            *reinterpret_cast<float4*>(&clds[r * 512 + p * 8]) =
                *reinterpret_cast<const float4*>(Cs + (size_t)(kc + r) * 512 + col * 8);
        }
        __syncthreads();

        f32x4 acc[4];
        #pragma unroll
        for (int kt = 0; kt < 4; kt++) acc[kt] = (f32x4){0.f, 0.f, 0.f, 0.f};

        #pragma unroll
        for (int s = 0; s < 8; s++) {
            #pragma unroll
            for (int kt = 0; kt < 4; kt++) {
                int kl = kt * 16 + lm;
                int chi = (4 * s + lg) ^ (kl & 7);
                fragA bhi = *reinterpret_cast<const fragA*>(&clds[kl * 512 + chi * 8]);
                fragA blo = *reinterpret_cast<const fragA*>(&clds[kl * 512 + (32 + chi) * 8]);
                acc[kt] = __builtin_amdgcn_mfma_f32_16x16x32_bf16(a_hi[s], bhi, acc[kt], 0, 0, 0);
                acc[kt] = __builtin_amdgcn_mfma_f32_16x16x32_bf16(a_lo[s], bhi, acc[kt], 0, 0, 0);
                acc[kt] = __builtin_amdgcn_mfma_f32_16x16x32_bf16(a_hi[s], blo, acc[kt], 0, 0, 0);
            }
        }

        #pragma unroll
        for (int kt = 0; kt < 4; kt++) {
            int k = kc + kt * 16 + lm;
            float cs = csq[k];
            #pragma unroll
            for (int r = 0; r < 4; r++) {
                float dist = (xs_r[r] + cs) - 2.0f * acc[kt][r];
                if (dist < d1[r] || (dist == d1[r] && k < k1[r])) {
                    d2[r] = d1[r]; d1[r] = dist; k1[r] = k;
                } else if (dist < d2[r]) {
                    d2[r] = dist;
                }
            }
        }
    }

    #pragma unroll
    for (int r = 0; r < 4; r++) {
        float bd1 = d1[r], bd2 = d2[r];
        int bk1 = k1[r];
        #pragma unroll
        for (int m = 1; m < 16; m <<= 1) {
            float od1 = __shfl_xor(bd1, m);
            int ok1 = __shfl_xor(bk1, m);
            float od2 = __shfl_xor(bd2, m);
            if (od1 < bd1 || (od1 == bd1 && ok1 < bk1)) {
                bd2 = fminf(bd1, od2); bd1 = od1; bk1 = ok1;
            } else {
                bd2 = fminf(bd2, od1);
            }
        }
        if (lm == 0) {
            int row = row0 + w * 16 + lg * 4 + r;
            indices[row] = bk1;
            if (bd2 - bd1 < MARGIN) {
                int pos = atomicAdd(flag_cnt, 1);
                if (pos < nrows_total) flag_list[pos] = row;
            }
        }
    }
}

// ============ exact fp32 recompute for flagged (near-tie) rows ============
__global__ __launch_bounds__(256) void exact_recheck_kernel(
        const float* __restrict__ X, const float* __restrict__ C,
        const float* __restrict__ xsq, const float* __restrict__ csq,
        const int* __restrict__ flag_cnt, const int* __restrict__ flag_list,
        int* __restrict__ indices, int nrows_total) {
    __shared__ float xlds[16][256];
    __shared__ float xsh[16];
    __shared__ unsigned long long best[16];
    int cnt = *flag_cnt;
    if (cnt > nrows_total) cnt = nrows_total;
    int tid = threadIdx.x;

    for (int base = blockIdx.x * 16; base < cnt; base += gridDim.x * 16) {
        int nr = min(16, cnt - base);
        __syncthreads();
        for (int e = tid; e < nr * 64; e += 256) {
            int r = e >> 6, c4 = e & 63;
            int row = flag_list[base + r];
            reinterpret_cast<float4*>(xlds[r])[c4] =
                reinterpret_cast<const float4*>(X + (size_t)row * DDIM)[c4];
        }
        if (tid < nr) xsh[tid] = xsq[flag_list[base + tid]];
        if (tid < 16) best[tid] = 0xFFFFFFFFFFFFFFFFULL;
        __syncthreads();

        for (int j = 0; j < 4; j++) {
            int k = tid + 256 * j;
            const float* crow = C + (size_t)k * DDIM;
            float acc[16];
            #pragma unroll
            for (int r = 0; r < 16; r++) acc[r] = 0.f;
            for (int d4 = 0; d4 < 64; d4++) {
                float4 cv = reinterpret_cast<const float4*>(crow)[d4];
                #pragma unroll
                for (int r = 0; r < 16; r++) {
                    float4 xv = reinterpret_cast<const float4*>(xlds[r])[d4];
                    acc[r] += xv.x * cv.x; acc[r] += xv.y * cv.y;
                    acc[r] += xv.z * cv.z; acc[r] += xv.w * cv.w;
                }
            }
            float cs = csq[k];
            #pragma unroll
            for (int r = 0; r < 16; r++) {
                float t = xsh[r] + cs;
                float dist = t - 2.0f * acc[r];
                unsigned long long pk =
                    ((unsigned long long)__float_as_uint(dist) << 32) | (unsigned)k;
                atomicMin(&best[r], pk);
            }
        }
        __syncthreads();
        if (tid < nr) indices[flag_list[base + tid]] = (int)(best[tid] & 0xFFFFFFFFULL);
    }
}

// ============ counting-sort segmented sum (replaces atomic scatter) ============
__global__ void hist_kernel(const int* __restrict__ idx, int* __restrict__ counts) {
    int i = blockIdx.x * 256 + threadIdx.x;
    atomicAdd(&counts[idx[i]], 1);
}

__global__ void prefix_kernel(const int* __restrict__ counts, int* __restrict__ offs,
                              int* __restrict__ cursor) {
    __shared__ int a[KCODES];
    int t = threadIdx.x;
    int v = counts[t];
    a[t] = v;
    __syncthreads();
    for (int s = 1; s < KCODES; s <<= 1) {
        int x = (t >= s) ? a[t - s] : 0;
        __syncthreads();
        a[t] += x;
        __syncthreads();
    }
    int excl = a[t] - v;
    offs[t] = excl;
    cursor[t] = excl;
}

__global__ void scatter_pos_kernel(const int* __restrict__ idx, int* __restrict__ cursor,
                                   int* __restrict__ sorted) {
    int i = blockIdx.x * 256 + threadIdx.x;
    int k = idx[i];
    int pos = atomicAdd(&cursor[k], 1);
    sorted[pos] = i;
}

// one block per code k: sum rows (no atomics), then fused EMA + divide
__global__ __launch_bounds__(256) void segsum_ema_kernel(
        const float* __restrict__ Z, const int* __restrict__ sorted,
        const int* __restrict__ offs, const int* __restrict__ counts,
        const float* __restrict__ ema_count, const float* __restrict__ ema_w,
        float* __restrict__ emb_new, float* __restrict__ cnt_new,
        float* __restrict__ w_new) {
    int k = blockIdx.x;
    int t = threadIdx.x;     // d index
    int start = offs[k];
    int cnt = counts[k];

    float acc = 0.f;
    int j = 0;
    for (; j + 4 <= cnt; j += 4) {
        int r0 = sorted[start + j + 0];
        int r1 = sorted[start + j + 1];
        int r2 = sorted[start + j + 2];
        int r3 = sorted[start + j + 3];
        float v0 = Z[(size_t)r0 * DDIM + t];
        float v1 = Z[(size_t)r1 * DDIM + t];
        float v2 = Z[(size_t)r2 * DDIM + t];
        float v3 = Z[(size_t)r3 * DDIM + t];
        acc += v0; acc += v1; acc += v2; acc += v3;
    }
    for (; j < cnt; j++) {
        int r = sorted[start + j];
        acc += Z[(size_t)r * DDIM + t];
    }

    const float DEC = 0.99f;
    const float OMD = (float)(1.0 - 0.99);
    float cn = __fadd_rn(__fmul_rn(DEC, ema_count[k]), __fmul_rn(OMD, (float)cnt));
    float wn = __fadd_rn(__fmul_rn(DEC, ema_w[(size_t)k * DDIM + t]), __fmul_rn(OMD, acc));
    w_new[(size_t)k * DDIM + t] = wn;
    emb_new[(size_t)k * DDIM + t] = __fdiv_rn(wn, cn);
    if (t == 0) cnt_new[k] = cn;
}

// ============ gathers ============
__global__ void gather_kernel(const float* __restrict__ emb, const float* __restrict__ emb_new,
                              const int* __restrict__ idx, float* __restrict__ zq,
                              float* __restrict__ zqb) {
    int row = blockIdx.x * 4 + (threadIdx.x >> 6);
    int lane = threadIdx.x & 63;
    int k = idx[row];
    float4 a = reinterpret_cast<const float4*>(emb + (size_t)k * DDIM)[lane];
    float4 b = reinterpret_cast<const float4*>(emb_new + (size_t)k * DDIM)[lane];
    reinterpret_cast<float4*>(zq + (size_t)row * DDIM)[lane] = a;
    reinterpret_cast<float4*>(zqb + (size_t)row * DDIM)[lane] = b;
}

// ============ round-2 fallback kernels (used only if ws too small) ============
__global__ void row_sqnorm_kernel(const float* __restrict__ X, float* __restrict__ out, int nrows) {
    int row = blockIdx.x * 4 + (threadIdx.x >> 6);
    if (row >= nrows) return;
    int lane = threadIdx.x & 63;
    float4 v = reinterpret_cast<const float4*>(X + (size_t)row * DDIM)[lane];
    double s = (double)v.x * v.x + (double)v.y * v.y + (double)v.z * v.z + (double)v.w * v.w;
    #pragma unroll
    for (int off = 32; off > 0; off >>= 1) s += __shfl_down(s, off);
    if (lane == 0) out[row] = (float)s;
}

#define BR 64
#define KC 128
#define DC 32
#define PAD 36

__global__ __launch_bounds__(256) void argmin_kernel(
        const float* __restrict__ X, const float* __restrict__ C,
        const float* __restrict__ xsq, const float* __restrict__ csq,
        int* __restrict__ indices) {
    __shared__ float xt[BR][PAD];
    __shared__ float ct[KC][PAD];
    int tid = threadIdx.x;
    int tx = tid & 15;
    int ty = tid >> 4;
    int row0 = blockIdx.x * BR;
    float xs[4];
    #pragma unroll
    for (int i = 0; i < 4; i++) xs[i] = xsq[row0 + i * 16 + ty];
    float bestd[4]; int bestk[4];
    #pragma unroll
    for (int i = 0; i < 4; i++) { bestd[i] = 3.0e38f; bestk[i] = 0; }
    for (int kc = 0; kc < KCODES; kc += KC) {
        float acc[4][8];
        #pragma unroll
        for (int i = 0; i < 4; i++)
            #pragma unroll
            for (int j = 0; j < 8; j++) acc[i][j] = 0.0f;
        for (int dt = 0; dt < DDIM; dt += DC) {
            __syncthreads();
            #pragma unroll
            for (int it = 0; it < 2; it++) {
                int e = it * 256 + tid;
                int r = e >> 3, c4 = e & 7;
                *reinterpret_cast<float4*>(&xt[r][c4 * 4]) = ld4(X + (size_t)(row0 + r) * DDIM + dt + c4 * 4);
            }
            #pragma unroll
            for (int it = 0; it < 4; it++) {
                int e = it * 256 + tid;
                int r = e >> 3, c4 = e & 7;
                *reinterpret_cast<float4*>(&ct[r][c4 * 4]) = ld4(C + (size_t)(kc + r) * DDIM + dt + c4 * 4);
            }
            __syncthreads();
            for (int d4 = 0; d4 < DC; d4 += 4) {
                float4 xv[4], cv[8];
                #pragma unroll
                for (int i = 0; i < 4; i++) xv[i] = *reinterpret_cast<const float4*>(&xt[i * 16 + ty][d4]);
                #pragma unroll
                for (int j = 0; j < 8; j++) cv[j] = *reinterpret_cast<const float4*>(&ct[j * 16 + tx][d4]);
                #pragma unroll
                for (int i = 0; i < 4; i++)
                    #pragma unroll
                    for (int j = 0; j < 8; j++) {
                        float a = acc[i][j];
                        a += xv[i].x * cv[j].x; a += xv[i].y * cv[j].y;
                        a += xv[i].z * cv[j].z; a += xv[i].w * cv[j].w;
                        acc[i][j] = a;
                    }
            }
        }
        float cs_r[8];
        #pragma unroll
        for (int j = 0; j < 8; j++) cs_r[j] = csq[kc + j * 16 + tx];
        #pragma unroll
        for (int i = 0; i < 4; i++) {
            float bd = 3.0e38f; int bk = 0;
            #pragma unroll
            for (int j = 0; j < 8; j++) {
                int kk = kc + j * 16 + tx;
                float t = xs[i] + cs_r[j];
                float dist = t - 2.0f * acc[i][j];
                if (dist < bd || (dist == bd && kk < bk)) { bd = dist; bk = kk; }
            }
            #pragma unroll
            for (int m = 1; m < 16; m <<= 1) {
                float od = __shfl_xor(bd, m);
                int ok = __shfl_xor(bk, m);
                if (od < bd || (od == bd && ok < bk)) { bd = od; bk = ok; }
            }
            if (bd < bestd[i] || (bd == bestd[i] && bk < bestk[i])) { bestd[i] = bd; bestk[i] = bk; }
        }
    }
    if (tx == 0) {
        #pragma unroll
        for (int i = 0; i < 4; i++) indices[row0 + i * 16 + ty] = bestk[i];
    }
}

__global__ void scatter_kernel(const float* __restrict__ Z, const int* __restrict__ idx,
                               int* __restrict__ counts, float* __restrict__ dw) {
    int row = blockIdx.x * 4 + (threadIdx.x >> 6);
    int lane = threadIdx.x & 63;
    int k = idx[row];
    float4 v = reinterpret_cast<const float4*>(Z + (size_t)row * DDIM)[lane];
    float* dst = dw + (size_t)k * DDIM + lane * 4;
    atomicAdd(dst + 0, v.x);
    atomicAdd(dst + 1, v.y);
    atomicAdd(dst + 2, v.z);
    atomicAdd(dst + 3, v.w);
    if (lane == 0) atomicAdd(&counts[k], 1);
}

__global__ void ema_kernel(const float* __restrict__ ema_count, const float* __restrict__ ema_w,
                           const int* __restrict__ counts, const float* __restrict__ dw,
                           float* __restrict__ emb_new, float* __restrict__ cnt_new,
                           float* __restrict__ w_new) {
    const float DEC = 0.99f;
    const float OMD = (float)(1.0 - 0.99);
    int i = blockIdx.x * 256 + threadIdx.x;
    int k = i >> 6;
    float cf = (float)counts[k];
    float cn = __fadd_rn(__fmul_rn(DEC, ema_count[k]), __fmul_rn(OMD, cf));
    float4 w = reinterpret_cast<const float4*>(ema_w)[i];
    float4 d = reinterpret_cast<const float4*>(dw)[i];
    float4 wn, en;
    wn.x = __fadd_rn(__fmul_rn(DEC, w.x), __fmul_rn(OMD, d.x));
    wn.y = __fadd_rn(__fmul_rn(DEC, w.y), __fmul_rn(OMD, d.y));
    wn.z = __fadd_rn(__fmul_rn(DEC, w.z), __fmul_rn(OMD, d.z));
    wn.w = __fadd_rn(__fmul_rn(DEC, w.w), __fmul_rn(OMD, d.w));
    en.x = __fdiv_rn(wn.x, cn);
    en.y = __fdiv_rn(wn.y, cn);
    en.z = __fdiv_rn(wn.z, cn);
    en.w = __fdiv_rn(wn.w, cn);
    reinterpret_cast<float4*>(w_new)[i] = wn;
    reinterpret_cast<float4*>(emb_new)[i] = en;
    if ((i & 63) == 0) cnt_new[k] = cn;
}

extern "C" void kernel_launch(void* const* d_in, const int* in_sizes, int n_in,
                              void* d_out, int out_size, void* d_ws, size_t ws_size,
                              hipStream_t stream) {
    const float* x = (const float*)d_in[0];
    const float* z = (const float*)d_in[1];
    const float* emb = (const float*)d_in[2];
    const float* ema_count = (const float*)d_in[3];
    const float* ema_w = (const float*)d_in[4];

    const int N = in_sizes[0] / DDIM;   // 65536
    const int K = in_sizes[3];          // 1024

    float* out = (float*)d_out;
    float* zq = out;
    float* zqb = zq + (size_t)N * DDIM;
    float* emb_new = zqb + (size_t)N * DDIM;
    float* cnt_new = emb_new + (size_t)K * DDIM;
    float* w_new = cnt_new + K;

    // workspace layout
    char* wsb = (char*)d_ws;
    size_t off = 0;
    ushort* xsplit = (ushort*)(wsb + off); off += (size_t)N * 512 * 2;      // 64 MiB
    ushort* csplit = (ushort*)(wsb + off); off += (size_t)K * 512 * 2;      // 1 MiB
    float* xsq = (float*)(wsb + off); off += (size_t)N * 4;
    float* csq = (float*)(wsb + off); off += (size_t)K * 4;
    int* indices = (int*)(wsb + off); off += (size_t)N * 4;
    int* flag_list = (int*)(wsb + off); off += (size_t)N * 4;
    int* sorted = (int*)(wsb + off); off += (size_t)N * 4;
    int* offs = (int*)(wsb + off); off += (size_t)K * 4;
    int* counts = (int*)(wsb + off); off += (size_t)K * 4;
    int* cursor = (int*)(wsb + off); off += (size_t)K * 4;
    int* flag_cnt = (int*)(wsb + off); off += 16;
    size_t need = off;

    if (ws_size >= need) {
        // zero counts + cursor + flag_cnt (contiguous)
        hipMemsetAsync(counts, 0, (size_t)K * 4 * 2 + 16, stream);
        split_sqnorm_kernel<<<N / 4, 256, 0, stream>>>(x, xsplit, xsq, N);
        split_sqnorm_kernel<<<K / 4, 256, 0, stream>>>(emb, csplit, csq, K);
        argmin_mfma_kernel<<<N / 64, 256, 0, stream>>>(xsplit, csplit, xsq, csq,
                                                       indices, flag_cnt, flag_list, N);
        exact_recheck_kernel<<<128, 256, 0, stream>>>(x, emb, xsq, csq,
                                                      flag_cnt, flag_list, indices, N);
        hist_kernel<<<N / 256, 256, 0, stream>>>(indices, counts);
        prefix_kernel<<<1, KCODES, 0, stream>>>(counts, offs, cursor);
        scatter_pos_kernel<<<N / 256, 256, 0, stream>>>(indices, cursor, sorted);
        segsum_ema_kernel<<<K, 256, 0, stream>>>(z, sorted, offs, counts,
                                                 ema_count, ema_w,
                                                 emb_new, cnt_new, w_new);
        gather_kernel<<<N / 4, 256, 0, stream>>>(emb, emb_new, indices, zq, zqb);
    } else {
        // fallback: round-2 validated fp32 path
        float* f_xsq = (float*)d_ws;
        float* f_csq = f_xsq + N;
        int* f_indices = (int*)(f_csq + K);
        int* f_counts = f_indices + N;
        float* f_dw = (float*)(f_counts + K);
        hipMemsetAsync(f_counts, 0, (size_t)(K + (size_t)K * DDIM) * sizeof(float), stream);
        row_sqnorm_kernel<<<N / 4, 256, 0, stream>>>(x, f_xsq, N);
        row_sqnorm_kernel<<<K / 4, 256, 0, stream>>>(emb, f_csq, K);
        argmin_kernel<<<N / BR, 256, 0, stream>>>(x, emb, f_xsq, f_csq, f_indices);
        scatter_kernel<<<N / 4, 256, 0, stream>>>(z, f_indices, f_counts, f_dw);
        ema_kernel<<<(K * DDIM / 4) / 256, 256, 0, stream>>>(ema_count, ema_w, f_counts, f_dw,
                                                             emb_new, cnt_new, w_new);
        gather_kernel<<<N / 4, 256, 0, stream>>>(emb, emb_new, f_indices, zq, zqb);
    }
}

// Round 6
// 481.871 us; speedup vs baseline: 1.7814x; 1.1366x over previous
//
#include <hip/hip_runtime.h>

#define DDIM 256
#define KCODES 1024
#define MARGIN 2.0e-4f

typedef __attribute__((ext_vector_type(8))) short fragA;
typedef __attribute__((ext_vector_type(4))) float f32x4;

static __device__ __forceinline__ float4 ld4(const float* p) {
    return *reinterpret_cast<const float4*>(p);
}

static __device__ __forceinline__ ushort bf16_rne(float f) {
    unsigned bits = __float_as_uint(f);
    unsigned r = bits + 0x7FFFu + ((bits >> 16) & 1u);
    return (ushort)(r >> 16);
}

// ============ fused split (hi/lo bf16 planes) + row squared norm ============
__global__ void split_sqnorm_kernel(const float* __restrict__ X, ushort* __restrict__ Xs,
                                    float* __restrict__ out, int nrows) {
    int row = blockIdx.x * 4 + (threadIdx.x >> 6);
    if (row >= nrows) return;
    int lane = threadIdx.x & 63;
    float4 v = reinterpret_cast<const float4*>(X + (size_t)row * DDIM)[lane];
    double s = (double)v.x * v.x + (double)v.y * v.y + (double)v.z * v.z + (double)v.w * v.w;
    #pragma unroll
    for (int off = 32; off > 0; off >>= 1) s += __shfl_down(s, off);
    if (lane == 0) out[row] = (float)s;

    float fv[4] = {v.x, v.y, v.z, v.w};
    ushort hb[4], lb[4];
    #pragma unroll
    for (int i = 0; i < 4; i++) {
        hb[i] = bf16_rne(fv[i]);
        float hf = __uint_as_float((unsigned)hb[i] << 16);
        lb[i] = bf16_rne(fv[i] - hf);
    }
    ushort4 hi = make_ushort4(hb[0], hb[1], hb[2], hb[3]);
    ushort4 lo = make_ushort4(lb[0], lb[1], lb[2], lb[3]);
    *reinterpret_cast<ushort4*>(Xs + (size_t)row * 512 + lane * 4) = hi;
    *reinterpret_cast<ushort4*>(Xs + (size_t)row * 512 + 256 + lane * 4) = lo;
}

// ============ MFMA argmin: dists[n,k] via 3-pass split-bf16, top-2 tracking ============
__global__ __launch_bounds__(256) void argmin_mfma_kernel(
        const ushort* __restrict__ Xs, const ushort* __restrict__ Cs,
        const float* __restrict__ xsq, const float* __restrict__ csq,
        int* __restrict__ indices, int* __restrict__ flag_cnt,
        int* __restrict__ flag_list, int nrows_total) {
    __shared__ ushort clds[64 * 512];   // 64 KB

    int tid = threadIdx.x;
    int w = tid >> 6;
    int l = tid & 63;
    int lm = l & 15;
    int lg = l >> 4;
    int row0 = blockIdx.x * 64;

    const ushort* xrow = Xs + (size_t)(row0 + w * 16 + lm) * 512;
    fragA a_hi[8], a_lo[8];
    #pragma unroll
    for (int s = 0; s < 8; s++) {
        a_hi[s] = *reinterpret_cast<const fragA*>(xrow + s * 32 + lg * 8);
        a_lo[s] = *reinterpret_cast<const fragA*>(xrow + 256 + s * 32 + lg * 8);
    }

    float xs_r[4];
    #pragma unroll
    for (int r = 0; r < 4; r++) xs_r[r] = xsq[row0 + w * 16 + lg * 4 + r];

    float d1[4], d2[4];
    int k1[4];
    #pragma unroll
    for (int r = 0; r < 4; r++) { d1[r] = 3.0e38f; d2[r] = 3.0e38f; k1[r] = 0; }

    for (int kc = 0; kc < KCODES; kc += 64) {
        __syncthreads();
        #pragma unroll
        for (int it = 0; it < 16; it++) {
            int c = it * 256 + tid;
            int r = c >> 6, col = c & 63;
            int p = (col & 32) | ((col & 31) ^ (r & 7));
            *reinterpret_cast<float4*>(&clds[r * 512 + p * 8]) =
                *reinterpret_cast<const float4*>(Cs + (size_t)(kc + r) * 512 + col * 8);
        }
        __syncthreads();

        f32x4 acc[4];
        #pragma unroll
        for (int kt = 0; kt < 4; kt++) acc[kt] = (f32x4){0.f, 0.f, 0.f, 0.f};

        #pragma unroll
        for (int s = 0; s < 8; s++) {
            #pragma unroll
            for (int kt = 0; kt < 4; kt++) {
                int kl = kt * 16 + lm;
                int chi = (4 * s + lg) ^ (kl & 7);
                fragA bhi = *reinterpret_cast<const fragA*>(&clds[kl * 512 + chi * 8]);
                fragA blo = *reinterpret_cast<const fragA*>(&clds[kl * 512 + (32 + chi) * 8]);
                acc[kt] = __builtin_amdgcn_mfma_f32_16x16x32_bf16(a_hi[s], bhi, acc[kt], 0, 0, 0);
                acc[kt] = __builtin_amdgcn_mfma_f32_16x16x32_bf16(a_lo[s], bhi, acc[kt], 0, 0, 0);
                acc[kt] = __builtin_amdgcn_mfma_f32_16x16x32_bf16(a_hi[s], blo, acc[kt], 0, 0, 0);
            }
        }

        #pragma unroll
        for (int kt = 0; kt < 4; kt++) {
            int k = kc + kt * 16 + lm;
            float cs = csq[k];
            #pragma unroll
            for (int r = 0; r < 4; r++) {
                float dist = (xs_r[r] + cs) - 2.0f * acc[kt][r];
                if (dist < d1[r] || (dist == d1[r] && k < k1[r])) {
                    d2[r] = d1[r]; d1[r] = dist; k1[r] = k;
                } else if (dist < d2[r]) {
                    d2[r] = dist;
                }
            }
        }
    }

    #pragma unroll
    for (int r = 0; r < 4; r++) {
        float bd1 = d1[r], bd2 = d2[r];
        int bk1 = k1[r];
        #pragma unroll
        for (int m = 1; m < 16; m <<= 1) {
            float od1 = __shfl_xor(bd1, m);
            int ok1 = __shfl_xor(bk1, m);
            float od2 = __shfl_xor(bd2, m);
            if (od1 < bd1 || (od1 == bd1 && ok1 < bk1)) {
                bd2 = fminf(bd1, od2); bd1 = od1; bk1 = ok1;
            } else {
                bd2 = fminf(bd2, od1);
            }
        }
        if (lm == 0) {
            int row = row0 + w * 16 + lg * 4 + r;
            indices[row] = bk1;
            if (bd2 - bd1 < MARGIN) {
                int pos = atomicAdd(flag_cnt, 1);
                if (pos < nrows_total) flag_list[pos] = row;
            }
        }
    }
}

// ============ exact fp32 tile argmin for flagged rows (round-2 validated math) ============
#define BR 64
#define KC 128
#define DC 32
#define PAD 36

__global__ __launch_bounds__(256) void exact_tile_kernel(
        const float* __restrict__ X, const float* __restrict__ C,
        const float* __restrict__ xsq, const float* __restrict__ csq,
        const int* __restrict__ flag_cnt, const int* __restrict__ flag_list,
        int* __restrict__ indices, int nrows_total) {
    __shared__ float xt[BR][PAD];
    __shared__ float ct[KC][PAD];
    __shared__ int rowidx[BR];
    __shared__ float xsql[BR];

    int cnt = *flag_cnt;
    if (cnt > nrows_total) cnt = nrows_total;
    if (cnt <= 0) return;
    int ntiles = (cnt + BR - 1) >> 6;

    int tid = threadIdx.x;
    int tx = tid & 15;
    int ty = tid >> 4;

    for (int t = blockIdx.x; t < ntiles; t += gridDim.x) {
        int base = t * BR;
        __syncthreads();    // protect rowidx/xsql reuse from previous tile iteration
        if (tid < BR) {
            int p = base + tid;
            int row = flag_list[p < cnt ? p : base];   // pad by duplicating first row
            rowidx[tid] = row;
            xsql[tid] = xsq[row];
        }
        __syncthreads();

        float xs[4];
        #pragma unroll
        for (int i = 0; i < 4; i++) xs[i] = xsql[i * 16 + ty];

        float bestd[4]; int bestk[4];
        #pragma unroll
        for (int i = 0; i < 4; i++) { bestd[i] = 3.0e38f; bestk[i] = 0; }

        for (int kc = 0; kc < KCODES; kc += KC) {
            __syncthreads();
            #pragma unroll
            for (int it = 0; it < 2; it++) {
                int e = it * 256 + tid;
                int r = e >> 3, c4 = e & 7;
                int dt = (kc == 0) ? 0 : 0;   // dt handled below
                (void)dt;
                // staged per d-tile inside the dt loop below
                (void)r; (void)c4;
            }
            // (x/c staging happens per d-tile below)
            __syncthreads();

            float acc[4][8];
            #pragma unroll
            for (int i = 0; i < 4; i++)
                #pragma unroll
                for (int j = 0; j < 8; j++) acc[i][j] = 0.0f;

            for (int dt = 0; dt < DDIM; dt += DC) {
                __syncthreads();
                #pragma unroll
                for (int it = 0; it < 2; it++) {
                    int e = it * 256 + tid;
                    int r = e >> 3, c4 = e & 7;
                    *reinterpret_cast<float4*>(&xt[r][c4 * 4]) =
                        ld4(X + (size_t)rowidx[r] * DDIM + dt + c4 * 4);
                }
                #pragma unroll
                for (int it = 0; it < 4; it++) {
                    int e = it * 256 + tid;
                    int r = e >> 3, c4 = e & 7;
                    *reinterpret_cast<float4*>(&ct[r][c4 * 4]) =
                        ld4(C + (size_t)(kc + r) * DDIM + dt + c4 * 4);
                }
                __syncthreads();
                for (int d4 = 0; d4 < DC; d4 += 4) {
                    float4 xv[4], cv[8];
                    #pragma unroll
                    for (int i = 0; i < 4; i++)
                        xv[i] = *reinterpret_cast<const float4*>(&xt[i * 16 + ty][d4]);
                    #pragma unroll
                    for (int j = 0; j < 8; j++)
                        cv[j] = *reinterpret_cast<const float4*>(&ct[j * 16 + tx][d4]);
                    #pragma unroll
                    for (int i = 0; i < 4; i++)
                        #pragma unroll
                        for (int j = 0; j < 8; j++) {
                            float a = acc[i][j];
                            a += xv[i].x * cv[j].x; a += xv[i].y * cv[j].y;
                            a += xv[i].z * cv[j].z; a += xv[i].w * cv[j].w;
                            acc[i][j] = a;
                        }
                }
            }

            float cs_r[8];
            #pragma unroll
            for (int j = 0; j < 8; j++) cs_r[j] = csq[kc + j * 16 + tx];
            #pragma unroll
            for (int i = 0; i < 4; i++) {
                float bd = 3.0e38f; int bk = 0;
                #pragma unroll
                for (int j = 0; j < 8; j++) {
                    int kk = kc + j * 16 + tx;
                    float tt = xs[i] + cs_r[j];
                    float dist = tt - 2.0f * acc[i][j];
                    if (dist < bd || (dist == bd && kk < bk)) { bd = dist; bk = kk; }
                }
                #pragma unroll
                for (int m = 1; m < 16; m <<= 1) {
                    float od = __shfl_xor(bd, m);
                    int ok = __shfl_xor(bk, m);
                    if (od < bd || (od == bd && ok < bk)) { bd = od; bk = ok; }
                }
                if (bd < bestd[i] || (bd == bestd[i] && bk < bestk[i])) { bestd[i] = bd; bestk[i] = bk; }
            }
        }

        if (tx == 0) {
            #pragma unroll
            for (int i = 0; i < 4; i++) {
                int p = base + i * 16 + ty;
                if (p < cnt) indices[rowidx[i * 16 + ty]] = bestk[i];
            }
        }
    }
}

// ============ counting-sort segmented sum ============
__global__ void hist_kernel(const int* __restrict__ idx, int* __restrict__ counts) {
    int i = blockIdx.x * 256 + threadIdx.x;
    atomicAdd(&counts[idx[i]], 1);
}

__global__ void prefix_kernel(const int* __restrict__ counts, int* __restrict__ offs,
                              int* __restrict__ cursor) {
    __shared__ int a[KCODES];
    int t = threadIdx.x;
    int v = counts[t];
    a[t] = v;
    __syncthreads();
    for (int s = 1; s < KCODES; s <<= 1) {
        int x = (t >= s) ? a[t - s] : 0;
        __syncthreads();
        a[t] += x;
        __syncthreads();
    }
    int excl = a[t] - v;
    offs[t] = excl;
    cursor[t] = excl;
}

__global__ void scatter_pos_kernel(const int* __restrict__ idx, int* __restrict__ cursor,
                                   int* __restrict__ sorted) {
    int i = blockIdx.x * 256 + threadIdx.x;
    int k = idx[i];
    int pos = atomicAdd(&cursor[k], 1);
    sorted[pos] = i;
}

// one block per code k: sum rows (no atomics), then fused EMA + divide
__global__ __launch_bounds__(256) void segsum_ema_kernel(
        const float* __restrict__ Z, const int* __restrict__ sorted,
        const int* __restrict__ offs, const int* __restrict__ counts,
        const float* __restrict__ ema_count, const float* __restrict__ ema_w,
        float* __restrict__ emb_new, float* __restrict__ cnt_new,
        float* __restrict__ w_new) {
    int k = blockIdx.x;
    int t = threadIdx.x;
    int start = offs[k];
    int cnt = counts[k];

    float acc = 0.f;
    int j = 0;
    for (; j + 4 <= cnt; j += 4) {
        int r0 = sorted[start + j + 0];
        int r1 = sorted[start + j + 1];
        int r2 = sorted[start + j + 2];
        int r3 = sorted[start + j + 3];
        float v0 = Z[(size_t)r0 * DDIM + t];
        float v1 = Z[(size_t)r1 * DDIM + t];
        float v2 = Z[(size_t)r2 * DDIM + t];
        float v3 = Z[(size_t)r3 * DDIM + t];
        acc += v0; acc += v1; acc += v2; acc += v3;
    }
    for (; j < cnt; j++) {
        int r = sorted[start + j];
        acc += Z[(size_t)r * DDIM + t];
    }

    const float DEC = 0.99f;
    const float OMD = (float)(1.0 - 0.99);
    float cn = __fadd_rn(__fmul_rn(DEC, ema_count[k]), __fmul_rn(OMD, (float)cnt));
    float wn = __fadd_rn(__fmul_rn(DEC, ema_w[(size_t)k * DDIM + t]), __fmul_rn(OMD, acc));
    w_new[(size_t)k * DDIM + t] = wn;
    emb_new[(size_t)k * DDIM + t] = __fdiv_rn(wn, cn);
    if (t == 0) cnt_new[k] = cn;
}

// ============ gathers ============
__global__ void gather_kernel(const float* __restrict__ emb, const float* __restrict__ emb_new,
                              const int* __restrict__ idx, float* __restrict__ zq,
                              float* __restrict__ zqb) {
    int row = blockIdx.x * 4 + (threadIdx.x >> 6);
    int lane = threadIdx.x & 63;
    int k = idx[row];
    float4 a = reinterpret_cast<const float4*>(emb + (size_t)k * DDIM)[lane];
    float4 b = reinterpret_cast<const float4*>(emb_new + (size_t)k * DDIM)[lane];
    reinterpret_cast<float4*>(zq + (size_t)row * DDIM)[lane] = a;
    reinterpret_cast<float4*>(zqb + (size_t)row * DDIM)[lane] = b;
}

extern "C" void kernel_launch(void* const* d_in, const int* in_sizes, int n_in,
                              void* d_out, int out_size, void* d_ws, size_t ws_size,
                              hipStream_t stream) {
    const float* x = (const float*)d_in[0];
    const float* z = (const float*)d_in[1];
    const float* emb = (const float*)d_in[2];
    const float* ema_count = (const float*)d_in[3];
    const float* ema_w = (const float*)d_in[4];

    const int N = in_sizes[0] / DDIM;   // 65536
    const int K = in_sizes[3];          // 1024

    float* out = (float*)d_out;
    float* zq = out;
    float* zqb = zq + (size_t)N * DDIM;
    float* emb_new = zqb + (size_t)N * DDIM;
    float* cnt_new = emb_new + (size_t)K * DDIM;
    float* w_new = cnt_new + K;

    // workspace layout
    char* wsb = (char*)d_ws;
    size_t off = 0;
    ushort* xsplit = (ushort*)(wsb + off); off += (size_t)N * 512 * 2;      // 64 MiB
    ushort* csplit = (ushort*)(wsb + off); off += (size_t)K * 512 * 2;      // 1 MiB
    float* xsq = (float*)(wsb + off); off += (size_t)N * 4;
    float* csq = (float*)(wsb + off); off += (size_t)K * 4;
    int* indices = (int*)(wsb + off); off += (size_t)N * 4;
    int* flag_list = (int*)(wsb + off); off += (size_t)N * 4;
    int* sorted = (int*)(wsb + off); off += (size_t)N * 4;
    int* offs = (int*)(wsb + off); off += (size_t)K * 4;
    int* counts = (int*)(wsb + off); off += (size_t)K * 4;
    int* cursor = (int*)(wsb + off); off += (size_t)K * 4;
    int* flag_cnt = (int*)(wsb + off); off += 16;

    // zero counts + cursor + flag_cnt (contiguous)
    hipMemsetAsync(counts, 0, (size_t)K * 4 * 2 + 16, stream);
    split_sqnorm_kernel<<<N / 4, 256, 0, stream>>>(x, xsplit, xsq, N);
    split_sqnorm_kernel<<<K / 4, 256, 0, stream>>>(emb, csplit, csq, K);
    argmin_mfma_kernel<<<N / 64, 256, 0, stream>>>(xsplit, csplit, xsq, csq,
                                                   indices, flag_cnt, flag_list, N);
    exact_tile_kernel<<<128, 256, 0, stream>>>(x, emb, xsq, csq,
                                               flag_cnt, flag_list, indices, N);
    hist_kernel<<<N / 256, 256, 0, stream>>>(indices, counts);
    prefix_kernel<<<1, KCODES, 0, stream>>>(counts, offs, cursor);
    scatter_pos_kernel<<<N / 256, 256, 0, stream>>>(indices, cursor, sorted);
    segsum_ema_kernel<<<K, 256, 0, stream>>>(z, sorted, offs, counts,
                                             ema_count, ema_w,
                                             emb_new, cnt_new, w_new);
    gather_kernel<<<N / 4, 256, 0, stream>>>(emb, emb_new, indices, zq, zqb);
}

// Round 7
// 334.391 us; speedup vs baseline: 2.5670x; 1.4410x over previous
//
#include <hip/hip_runtime.h>

#define DDIM 256
#define KCODES 1024
#define MARGIN 2.0e-4f

typedef __attribute__((ext_vector_type(8))) short fragA;
typedef __attribute__((ext_vector_type(4))) float f32x4;

static __device__ __forceinline__ float4 ld4(const float* p) {
    return *reinterpret_cast<const float4*>(p);
}

static __device__ __forceinline__ ushort bf16_rne(float f) {
    unsigned bits = __float_as_uint(f);
    unsigned r = bits + 0x7FFFu + ((bits >> 16) & 1u);
    return (ushort)(r >> 16);
}

// ============ fused split (hi/lo bf16 planes) + row squared norm ============
__global__ void split_sqnorm_kernel(const float* __restrict__ X, ushort* __restrict__ Xs,
                                    float* __restrict__ out, int nrows) {
    int row = blockIdx.x * 4 + (threadIdx.x >> 6);
    if (row >= nrows) return;
    int lane = threadIdx.x & 63;
    float4 v = reinterpret_cast<const float4*>(X + (size_t)row * DDIM)[lane];
    double s = (double)v.x * v.x + (double)v.y * v.y + (double)v.z * v.z + (double)v.w * v.w;
    #pragma unroll
    for (int off = 32; off > 0; off >>= 1) s += __shfl_down(s, off);
    if (lane == 0) out[row] = (float)s;

    float fv[4] = {v.x, v.y, v.z, v.w};
    ushort hb[4], lb[4];
    #pragma unroll
    for (int i = 0; i < 4; i++) {
        hb[i] = bf16_rne(fv[i]);
        float hf = __uint_as_float((unsigned)hb[i] << 16);
        lb[i] = bf16_rne(fv[i] - hf);
    }
    ushort4 hi = make_ushort4(hb[0], hb[1], hb[2], hb[3]);
    ushort4 lo = make_ushort4(lb[0], lb[1], lb[2], lb[3]);
    *reinterpret_cast<ushort4*>(Xs + (size_t)row * 512 + lane * 4) = hi;
    *reinterpret_cast<ushort4*>(Xs + (size_t)row * 512 + 256 + lane * 4) = lo;
}

// ============ MFMA argmin: dists[n,k] via 3-pass split-bf16, top-2 tracking ============
__global__ __launch_bounds__(256) void argmin_mfma_kernel(
        const ushort* __restrict__ Xs, const ushort* __restrict__ Cs,
        const float* __restrict__ xsq, const float* __restrict__ csq,
        int* __restrict__ indices, int* __restrict__ flag_cnt,
        int* __restrict__ flag_list, int nrows_total) {
    __shared__ ushort clds[64 * 512];   // 64 KB

    int tid = threadIdx.x;
    int w = tid >> 6;
    int l = tid & 63;
    int lm = l & 15;
    int lg = l >> 4;
    int row0 = blockIdx.x * 64;

    const ushort* xrow = Xs + (size_t)(row0 + w * 16 + lm) * 512;
    fragA a_hi[8], a_lo[8];
    #pragma unroll
    for (int s = 0; s < 8; s++) {
        a_hi[s] = *reinterpret_cast<const fragA*>(xrow + s * 32 + lg * 8);
        a_lo[s] = *reinterpret_cast<const fragA*>(xrow + 256 + s * 32 + lg * 8);
    }

    float xs_r[4];
    #pragma unroll
    for (int r = 0; r < 4; r++) xs_r[r] = xsq[row0 + w * 16 + lg * 4 + r];

    float d1[4], d2[4];
    int k1[4];
    #pragma unroll
    for (int r = 0; r < 4; r++) { d1[r] = 3.0e38f; d2[r] = 3.0e38f; k1[r] = 0; }

    for (int kc = 0; kc < KCODES; kc += 64) {
        __syncthreads();
        #pragma unroll
        for (int it = 0; it < 16; it++) {
            int c = it * 256 + tid;
            int r = c >> 6, col = c & 63;
            int p = (col & 32) | ((col & 31) ^ (r & 7));
            *reinterpret_cast<float4*>(&clds[r * 512 + p * 8]) =
                *reinterpret_cast<const float4*>(Cs + (size_t)(kc + r) * 512 + col * 8);
        }
        __syncthreads();

        f32x4 acc[4];
        #pragma unroll
        for (int kt = 0; kt < 4; kt++) acc[kt] = (f32x4){0.f, 0.f, 0.f, 0.f};

        #pragma unroll
        for (int s = 0; s < 8; s++) {
            #pragma unroll
            for (int kt = 0; kt < 4; kt++) {
                int kl = kt * 16 + lm;
                int chi = (4 * s + lg) ^ (kl & 7);
                fragA bhi = *reinterpret_cast<const fragA*>(&clds[kl * 512 + chi * 8]);
                fragA blo = *reinterpret_cast<const fragA*>(&clds[kl * 512 + (32 + chi) * 8]);
                acc[kt] = __builtin_amdgcn_mfma_f32_16x16x32_bf16(a_hi[s], bhi, acc[kt], 0, 0, 0);
                acc[kt] = __builtin_amdgcn_mfma_f32_16x16x32_bf16(a_lo[s], bhi, acc[kt], 0, 0, 0);
                acc[kt] = __builtin_amdgcn_mfma_f32_16x16x32_bf16(a_hi[s], blo, acc[kt], 0, 0, 0);
            }
        }

        #pragma unroll
        for (int kt = 0; kt < 4; kt++) {
            int k = kc + kt * 16 + lm;
            float cs = csq[k];
            #pragma unroll
            for (int r = 0; r < 4; r++) {
                float dist = (xs_r[r] + cs) - 2.0f * acc[kt][r];
                if (dist < d1[r] || (dist == d1[r] && k < k1[r])) {
                    d2[r] = d1[r]; d1[r] = dist; k1[r] = k;
                } else if (dist < d2[r]) {
                    d2[r] = dist;
                }
            }
        }
    }

    #pragma unroll
    for (int r = 0; r < 4; r++) {
        float bd1 = d1[r], bd2 = d2[r];
        int bk1 = k1[r];
        #pragma unroll
        for (int m = 1; m < 16; m <<= 1) {
            float od1 = __shfl_xor(bd1, m);
            int ok1 = __shfl_xor(bk1, m);
            float od2 = __shfl_xor(bd2, m);
            if (od1 < bd1 || (od1 == bd1 && ok1 < bk1)) {
                bd2 = fminf(bd1, od2); bd1 = od1; bk1 = ok1;
            } else {
                bd2 = fminf(bd2, od1);
            }
        }
        if (lm == 0) {
            int row = row0 + w * 16 + lg * 4 + r;
            indices[row] = bk1;
            if (bd2 - bd1 < MARGIN) {
                int pos = atomicAdd(flag_cnt, 1);
                if (pos < nrows_total) flag_list[pos] = row;
            }
        }
    }
}

// ============ exact fp32 recheck: (64-row x 64-code) chunks + packed atomicMin ============
#define ECH 64                      // codes per chunk
#define NKCH (KCODES / ECH)         // 16 chunks

__global__ __launch_bounds__(256) void exact_chunk_kernel(
        const float* __restrict__ X, const float* __restrict__ C,
        const float* __restrict__ xsq, const float* __restrict__ csq,
        const int* __restrict__ flag_cnt, const int* __restrict__ flag_list,
        unsigned long long* __restrict__ best64, int nrows_total) {
    __shared__ float xt[64][36];
    __shared__ float ct[64][36];
    __shared__ int rowidx[64];
    __shared__ float xsql[64];

    int cnt = *flag_cnt;
    if (cnt > nrows_total) cnt = nrows_total;
    if (cnt <= 0) return;
    int ntiles = (cnt + 63) >> 6;
    int nunits = ntiles * NKCH;

    int tid = threadIdx.x;
    int tx = tid & 15;
    int ty = tid >> 4;

    for (int u = blockIdx.x; u < nunits; u += gridDim.x) {
        int t = u >> 4;               // row tile
        int kc = (u & 15) * ECH;      // code chunk base
        int base = t * 64;

        __syncthreads();
        if (tid < 64) {
            int p = base + tid;
            int row = flag_list[p < cnt ? p : base];   // pad: duplicate first row
            rowidx[tid] = row;
            xsql[tid] = xsq[row];
        }
        __syncthreads();

        float xs[4];
        #pragma unroll
        for (int i = 0; i < 4; i++) xs[i] = xsql[i * 16 + ty];

        float acc[4][4];
        #pragma unroll
        for (int i = 0; i < 4; i++)
            #pragma unroll
            for (int j = 0; j < 4; j++) acc[i][j] = 0.0f;

        for (int dt = 0; dt < DDIM; dt += 32) {
            __syncthreads();
            #pragma unroll
            for (int it = 0; it < 2; it++) {
                int e = it * 256 + tid;
                int r = e >> 3, c4 = e & 7;
                *reinterpret_cast<float4*>(&xt[r][c4 * 4]) =
                    ld4(X + (size_t)rowidx[r] * DDIM + dt + c4 * 4);
            }
            #pragma unroll
            for (int it = 0; it < 2; it++) {
                int e = it * 256 + tid;
                int r = e >> 3, c4 = e & 7;
                *reinterpret_cast<float4*>(&ct[r][c4 * 4]) =
                    ld4(C + (size_t)(kc + r) * DDIM + dt + c4 * 4);
            }
            __syncthreads();

            for (int d4 = 0; d4 < 32; d4 += 4) {
                float4 xv[4], cv[4];
                #pragma unroll
                for (int i = 0; i < 4; i++)
                    xv[i] = *reinterpret_cast<const float4*>(&xt[i * 16 + ty][d4]);
                #pragma unroll
                for (int j = 0; j < 4; j++)
                    cv[j] = *reinterpret_cast<const float4*>(&ct[j * 16 + tx][d4]);
                #pragma unroll
                for (int i = 0; i < 4; i++)
                    #pragma unroll
                    for (int j = 0; j < 4; j++) {
                        float a = acc[i][j];
                        a += xv[i].x * cv[j].x; a += xv[i].y * cv[j].y;
                        a += xv[i].z * cv[j].z; a += xv[i].w * cv[j].w;
                        acc[i][j] = a;
                    }
            }
        }

        float cs_r[4];
        #pragma unroll
        for (int j = 0; j < 4; j++) cs_r[j] = csq[kc + j * 16 + tx];

        #pragma unroll
        for (int i = 0; i < 4; i++) {
            float bd = 3.0e38f; int bk = 0;
            #pragma unroll
            for (int j = 0; j < 4; j++) {
                int kk = kc + j * 16 + tx;
                float tt = xs[i] + cs_r[j];
                float dist = tt - 2.0f * acc[i][j];
                if (dist < bd || (dist == bd && kk < bk)) { bd = dist; bk = kk; }
            }
            #pragma unroll
            for (int m = 1; m < 16; m <<= 1) {
                float od = __shfl_xor(bd, m);
                int ok = __shfl_xor(bk, m);
                if (od < bd || (od == bd && ok < bk)) { bd = od; bk = ok; }
            }
            if (tx == 0) {
                int p = base + i * 16 + ty;
                if (p < cnt) {
                    unsigned long long pk =
                        ((unsigned long long)__float_as_uint(bd) << 32) | (unsigned)bk;
                    atomicMin(&best64[p], pk);
                }
            }
        }
    }
}

__global__ void exact_finalize_kernel(const int* __restrict__ flag_cnt,
                                      const int* __restrict__ flag_list,
                                      const unsigned long long* __restrict__ best64,
                                      int* __restrict__ indices, int nrows_total) {
    int cnt = *flag_cnt;
    if (cnt > nrows_total) cnt = nrows_total;
    for (int i = blockIdx.x * 256 + threadIdx.x; i < cnt; i += gridDim.x * 256)
        indices[flag_list[i]] = (int)(best64[i] & 0xFFFFFFFFULL);
}

// ============ counting-sort segmented sum ============
__global__ void hist_kernel(const int* __restrict__ idx, int* __restrict__ counts) {
    int i = blockIdx.x * 256 + threadIdx.x;
    atomicAdd(&counts[idx[i]], 1);
}

__global__ void prefix_kernel(const int* __restrict__ counts, int* __restrict__ offs,
                              int* __restrict__ cursor) {
    __shared__ int a[KCODES];
    int t = threadIdx.x;
    int v = counts[t];
    a[t] = v;
    __syncthreads();
    for (int s = 1; s < KCODES; s <<= 1) {
        int x = (t >= s) ? a[t - s] : 0;
        __syncthreads();
        a[t] += x;
        __syncthreads();
    }
    int excl = a[t] - v;
    offs[t] = excl;
    cursor[t] = excl;
}

__global__ void scatter_pos_kernel(const int* __restrict__ idx, int* __restrict__ cursor,
                                   int* __restrict__ sorted) {
    int i = blockIdx.x * 256 + threadIdx.x;
    int k = idx[i];
    int pos = atomicAdd(&cursor[k], 1);
    sorted[pos] = i;
}

// one block per code k: sum rows (no atomics), then fused EMA + divide
__global__ __launch_bounds__(256) void segsum_ema_kernel(
        const float* __restrict__ Z, const int* __restrict__ sorted,
        const int* __restrict__ offs, const int* __restrict__ counts,
        const float* __restrict__ ema_count, const float* __restrict__ ema_w,
        float* __restrict__ emb_new, float* __restrict__ cnt_new,
        float* __restrict__ w_new) {
    int k = blockIdx.x;
    int t = threadIdx.x;
    int start = offs[k];
    int cnt = counts[k];

    float acc = 0.f;
    int j = 0;
    for (; j + 4 <= cnt; j += 4) {
        int r0 = sorted[start + j + 0];
        int r1 = sorted[start + j + 1];
        int r2 = sorted[start + j + 2];
        int r3 = sorted[start + j + 3];
        float v0 = Z[(size_t)r0 * DDIM + t];
        float v1 = Z[(size_t)r1 * DDIM + t];
        float v2 = Z[(size_t)r2 * DDIM + t];
        float v3 = Z[(size_t)r3 * DDIM + t];
        acc += v0; acc += v1; acc += v2; acc += v3;
    }
    for (; j < cnt; j++) {
        int r = sorted[start + j];
        acc += Z[(size_t)r * DDIM + t];
    }

    const float DEC = 0.99f;
    const float OMD = (float)(1.0 - 0.99);
    float cn = __fadd_rn(__fmul_rn(DEC, ema_count[k]), __fmul_rn(OMD, (float)cnt));
    float wn = __fadd_rn(__fmul_rn(DEC, ema_w[(size_t)k * DDIM + t]), __fmul_rn(OMD, acc));
    w_new[(size_t)k * DDIM + t] = wn;
    emb_new[(size_t)k * DDIM + t] = __fdiv_rn(wn, cn);
    if (t == 0) cnt_new[k] = cn;
}

// ============ gathers ============
__global__ void gather_kernel(const float* __restrict__ emb, const float* __restrict__ emb_new,
                              const int* __restrict__ idx, float* __restrict__ zq,
                              float* __restrict__ zqb) {
    int row = blockIdx.x * 4 + (threadIdx.x >> 6);
    int lane = threadIdx.x & 63;
    int k = idx[row];
    float4 a = reinterpret_cast<const float4*>(emb + (size_t)k * DDIM)[lane];
    float4 b = reinterpret_cast<const float4*>(emb_new + (size_t)k * DDIM)[lane];
    reinterpret_cast<float4*>(zq + (size_t)row * DDIM)[lane] = a;
    reinterpret_cast<float4*>(zqb + (size_t)row * DDIM)[lane] = b;
}

extern "C" void kernel_launch(void* const* d_in, const int* in_sizes, int n_in,
                              void* d_out, int out_size, void* d_ws, size_t ws_size,
                              hipStream_t stream) {
    const float* x = (const float*)d_in[0];
    const float* z = (const float*)d_in[1];
    const float* emb = (const float*)d_in[2];
    const float* ema_count = (const float*)d_in[3];
    const float* ema_w = (const float*)d_in[4];

    const int N = in_sizes[0] / DDIM;   // 65536
    const int K = in_sizes[3];          // 1024

    float* out = (float*)d_out;
    float* zq = out;
    float* zqb = zq + (size_t)N * DDIM;
    float* emb_new = zqb + (size_t)N * DDIM;
    float* cnt_new = emb_new + (size_t)K * DDIM;
    float* w_new = cnt_new + K;

    // workspace layout
    char* wsb = (char*)d_ws;
    size_t off = 0;
    ushort* xsplit = (ushort*)(wsb + off); off += (size_t)N * 512 * 2;      // 64 MiB
    ushort* csplit = (ushort*)(wsb + off); off += (size_t)K * 512 * 2;      // 1 MiB
    float* xsq = (float*)(wsb + off); off += (size_t)N * 4;
    float* csq = (float*)(wsb + off); off += (size_t)K * 4;
    int* indices = (int*)(wsb + off); off += (size_t)N * 4;
    int* flag_list = (int*)(wsb + off); off += (size_t)N * 4;
    int* sorted = (int*)(wsb + off); off += (size_t)N * 4;
    int* offs = (int*)(wsb + off); off += (size_t)K * 4;
    int* counts = (int*)(wsb + off); off += (size_t)K * 4;
    int* cursor = (int*)(wsb + off); off += (size_t)K * 4;
    int* flag_cnt = (int*)(wsb + off); off += 16;
    unsigned long long* best64 = (unsigned long long*)(wsb + off); off += (size_t)N * 8;

    // zero counts + cursor + flag_cnt (contiguous); init best64 to all-ones
    hipMemsetAsync(counts, 0, (size_t)K * 4 * 2 + 16, stream);
    hipMemsetAsync(best64, 0xFF, (size_t)N * 8, stream);
    split_sqnorm_kernel<<<N / 4, 256, 0, stream>>>(x, xsplit, xsq, N);
    split_sqnorm_kernel<<<K / 4, 256, 0, stream>>>(emb, csplit, csq, K);
    argmin_mfma_kernel<<<N / 64, 256, 0, stream>>>(xsplit, csplit, xsq, csq,
                                                   indices, flag_cnt, flag_list, N);
    exact_chunk_kernel<<<256, 256, 0, stream>>>(x, emb, xsq, csq,
                                                flag_cnt, flag_list, best64, N);
    exact_finalize_kernel<<<64, 256, 0, stream>>>(flag_cnt, flag_list, best64, indices, N);
    hist_kernel<<<N / 256, 256, 0, stream>>>(indices, counts);
    prefix_kernel<<<1, KCODES, 0, stream>>>(counts, offs, cursor);
    scatter_pos_kernel<<<N / 256, 256, 0, stream>>>(indices, cursor, sorted);
    segsum_ema_kernel<<<K, 256, 0, stream>>>(z, sorted, offs, counts,
                                             ema_count, ema_w,
                                             emb_new, cnt_new, w_new);
    gather_kernel<<<N / 4, 256, 0, stream>>>(emb, emb_new, indices, zq, zqb);
}